// Round 8
// baseline (152.107 us; speedup 1.0000x reference)
//
#include <hip/hip_runtime.h>
#include <stdint.h>

// CrossAttentionLayer: B=2, Q=256, N=16384, C=256, H=8, d=32
#define B_ 2
#define Q_ 256
#define N_ 16384
#define C_ 256
#define H_ 8
#define D_ 32
#define NC_ 32                      // attention split-N chunks (N/NC = 512 per block)
#define SCALE 0.17677669529663687f  // 1/sqrt(32)

typedef __bf16 bf16x8 __attribute__((ext_vector_type(8)));
typedef float f32x4 __attribute__((ext_vector_type(4)));

__device__ __forceinline__ uint16_t bfbits(float f) {
  union { __bf16 h; uint16_t u; } c;
  c.h = (__bf16)f;
  return c.u;
}
__device__ __forceinline__ uint16_t f2bf(float f) {
  union { float f; uint32_t u; } c; c.f = f;
  uint32_t r = c.u + 0x7FFFu + ((c.u >> 16) & 1u);  // RNE
  return (uint16_t)(r >> 16);
}
__device__ __forceinline__ uint32_t pk2(float a, float b) {
  return (uint32_t)f2bf(a) | ((uint32_t)f2bf(b) << 16);
}
__device__ __forceinline__ void lgkm0_barrier() {
  __builtin_amdgcn_sched_barrier(0);
  asm volatile("s_waitcnt lgkmcnt(0)" ::: "memory");
  __builtin_amdgcn_sched_barrier(0);
  __builtin_amdgcn_s_barrier();
  __builtin_amdgcn_sched_barrier(0);
}

// ---------------------------------------------------------------------------
// Kernel 1 "prep" (fused): blocks 0..95: in_proj_w (768x256) -> bf16;
// blocks 96..159: transpose out_proj_w -> woT; blocks 160..671: pack vid_mask
// -> bitmask (B,Q,N/32), bit=1 => blocked, with all-blocked fallback.
// ---------------------------------------------------------------------------
__global__ __launch_bounds__(256) void prep(const float* __restrict__ inw,
                                            const float* __restrict__ outw,
                                            const float* __restrict__ vm,
                                            uint16_t* __restrict__ wb,
                                            float* __restrict__ woT,
                                            uint32_t* __restrict__ mb) {
  __shared__ __align__(16) char sh[4352];
  const int bid = blockIdx.x;
  const int t = threadIdx.x;
  if (bid < 96) {
    const int i = (bid * 256 + t) * 8;
    const float4 a = *reinterpret_cast<const float4*>(inw + i);
    const float4 b = *reinterpret_cast<const float4*>(inw + i + 4);
    ushort4 lo = {bfbits(a.x), bfbits(a.y), bfbits(a.z), bfbits(a.w)};
    ushort4 hi = {bfbits(b.x), bfbits(b.y), bfbits(b.z), bfbits(b.w)};
    *reinterpret_cast<ushort4*>(wb + i) = lo;
    *reinterpret_cast<ushort4*>(wb + i + 4) = hi;
  } else if (bid < 160) {
    float(*s)[33] = reinterpret_cast<float(*)[33]>(sh);
    const int bb = bid - 96;
    const int bx = bb & 7, by = bb >> 3;
    const int r0 = by * 32, c0 = bx * 32;
    const int tr = t >> 5, tc = t & 31;
#pragma unroll
    for (int k = 0; k < 4; ++k)
      s[tr + 8 * k][tc] = outw[(size_t)(r0 + tr + 8 * k) * 256 + c0 + tc];
    __syncthreads();
#pragma unroll
    for (int k = 0; k < 4; ++k)
      woT[(size_t)(c0 + tr + 8 * k) * 256 + r0 + tc] = s[tc][tr + 8 * k];
  } else {
    uint8_t(*nib)[256] = reinterpret_cast<uint8_t(*)[256]>(sh);
    __shared__ int wcnt[4];
    __shared__ int tot;
    const int bq = bid - 160;
    const float* row = vm + (size_t)bq * N_;
    const int lane = t & 63;
    int cnt = 0;
#pragma unroll
    for (int i = 0; i < 16; ++i) {
      const float4 v = *reinterpret_cast<const float4*>(&row[i * 1024 + 4 * t]);
      const uint32_t nb = (v.x < 0.5f ? 1u : 0u) | (v.y < 0.5f ? 2u : 0u) |
                          (v.z < 0.5f ? 4u : 0u) | (v.w < 0.5f ? 8u : 0u);
      nib[i][t] = (uint8_t)nb;
      cnt += __popc(nb);
    }
    for (int o = 32; o > 0; o >>= 1) cnt += __shfl_down(cnt, o, 64);
    if (lane == 0) wcnt[t >> 6] = cnt;
    __syncthreads();
    if (t == 0) tot = wcnt[0] + wcnt[1] + wcnt[2] + wcnt[3];
    __syncthreads();
    const bool allb = (tot == N_);
    uint32_t* dst = mb + (size_t)bq * 512;
#pragma unroll
    for (int k = 0; k < 2; ++k) {
      const int w = k * 256 + t;
      const int i = w >> 5, tw = w & 31;
      const uint2 u = *reinterpret_cast<const uint2*>(&nib[i][8 * tw]);
      uint32_t y0 = u.x & 0x0F0F0F0Fu; y0 = y0 | (y0 >> 4);
      uint32_t y1 = u.y & 0x0F0F0F0Fu; y1 = y1 | (y1 >> 4);
      const uint32_t word = (y0 & 0xFFu) | (((y0 >> 16) & 0xFFu) << 8) |
                            ((y1 & 0xFFu) << 16) | (((y1 >> 16) & 0xFFu) << 24);
      dst[w] = allb ? 0u : word;
    }
  }
}

// ---------------------------------------------------------------------------
// Kernel 2 "kvqproj" (R7): granularity-fixed K/V projection.
// Blocks 0..255: tile = full 256 cout (K in waves 0-3, V in waves 4-7) x
// 128 n, K-loop cin 8 steps x 32. Per step each cin row is read as 512 B
// CONTIGUOUS (2 back-to-back 256B wave-instructions) -- vs 128 B before.
// Adjacent blocks read adjacent 512B segments of the same rows.
// Pipeline: 2-step register lookahead (~64 KB in flight/CU), weights for
// s+1 issued before act(s+2) so COMPUTE's weight wait never drains the
// activation stream (in-order vmcnt). lgkm-only barrier, dbuf LDS.
// Blocks 256..263: Q projection via MFMA (64 q-rows each).
// ---------------------------------------------------------------------------
__global__ __launch_bounds__(512, 1) void kvqproj(const float* __restrict__ vf,
                                                  const float* __restrict__ pe,
                                                  const float* __restrict__ queries,
                                                  const float* __restrict__ qembed,
                                                  const uint16_t* __restrict__ wkv,
                                                  const float* __restrict__ bias,
                                                  uint16_t* __restrict__ Kb,
                                                  uint16_t* __restrict__ Vb,
                                                  uint16_t* __restrict__ Qb) {
  const int bid = blockIdx.x;
  const int t = threadIdx.x, wid = t >> 6, lane = t & 63;
  const int g = lane >> 4, c15 = lane & 15;

  if (bid < 256) {
    __shared__ __align__(16) uint16_t XP[2][128][34];
    __shared__ __align__(16) uint16_t XV[2][128][34];

    const int b = bid >> 7, nt = bid & 127;
    const int n0 = nt * 128;
    const bool isK = wid < 4;
    const int wc = wid & 3;
    const uint16_t* Wsec = wkv + (isK ? 256 * C_ : 512 * C_) + (size_t)(wc * 64 + c15) * C_;

    f32x4 acc[32];
    if (isK) {
#pragma unroll
      for (int cf = 0; cf < 4; ++cf) {
        f32x4 iv;
#pragma unroll
        for (int j = 0; j < 4; ++j) iv[j] = bias[256 + wc * 64 + cf * 16 + 4 * g + j];
#pragma unroll
        for (int nf = 0; nf < 8; ++nf) acc[cf * 8 + nf] = iv;
      }
    } else {
#pragma unroll
      for (int cf = 0; cf < 4; ++cf) {
        const float bv = bias[512 + wc * 64 + cf * 16 + c15];
        const f32x4 iv = {bv, bv, bv, bv};
#pragma unroll
        for (int nf = 0; nf < 8; ++nf) acc[nf * 4 + cf] = iv;
      }
    }

    const int scin = t >> 4, nq = t & 15;
    const float* Xb = vf + ((size_t)b * C_ + scin) * N_ + n0 + nq * 4;
    const float* Pb = pe + ((size_t)b * C_ + scin) * N_ + n0 + nq * 4;

    float4 xA[2], pA[2], xB[2], pB[2];
    bf16x8 Wa[4], Wz[4];

#define LOADW(W, s)                                                          \
    {                                                                        \
      _Pragma("unroll") for (int cf = 0; cf < 4; ++cf)                       \
          W[cf] = *(const bf16x8*)(Wsec + (size_t)cf * 16 * C_ + (s) * 32 + g * 8); \
    }

#define LOADA(XA, PA, s)                                                     \
    {                                                                        \
      _Pragma("unroll") for (int j = 0; j < 2; ++j) {                        \
        XA[j] = *(const float4*)(Xb + (size_t)(s) * 32 * N_ + j * 64);       \
        PA[j] = *(const float4*)(Pb + (size_t)(s) * 32 * N_ + j * 64);       \
      }                                                                      \
    }

#define WRITEA(XA, PA, buf)                                                  \
    {                                                                        \
      _Pragma("unroll") for (int j = 0; j < 2; ++j) {                        \
        const float* xf_ = (const float*)&XA[j];                             \
        const float* pf_ = (const float*)&PA[j];                             \
        _Pragma("unroll") for (int i = 0; i < 4; ++i) {                      \
          const int n_ = j * 64 + nq * 4 + i;                                \
          XP[buf][n_][scin] = f2bf(xf_[i] + pf_[i]);                         \
          XV[buf][n_][scin] = f2bf(xf_[i]);                                  \
        }                                                                    \
      }                                                                      \
    }

#define COMPUTE(W, buf)                                                      \
    {                                                                        \
      if (isK) {                                                             \
        _Pragma("unroll") for (int nf = 0; nf < 8; ++nf) {                   \
          const int r_ = nf * 16 + c15;                                      \
          const bf16x8 Bf_ = *(const bf16x8*)&XP[buf][r_][g * 8];            \
          _Pragma("unroll") for (int cf = 0; cf < 4; ++cf)                   \
              acc[cf * 8 + nf] = __builtin_amdgcn_mfma_f32_16x16x32_bf16(    \
                  W[cf], Bf_, acc[cf * 8 + nf], 0, 0, 0);                    \
        }                                                                    \
      } else {                                                               \
        _Pragma("unroll") for (int nf = 0; nf < 8; ++nf) {                   \
          const int r_ = nf * 16 + c15;                                      \
          const bf16x8 Af_ = *(const bf16x8*)&XV[buf][r_][g * 8];            \
          _Pragma("unroll") for (int cf = 0; cf < 4; ++cf)                   \
              acc[nf * 4 + cf] = __builtin_amdgcn_mfma_f32_16x16x32_bf16(    \
                  Af_, W[cf], acc[nf * 4 + cf], 0, 0, 0);                    \
        }                                                                    \
      }                                                                      \
    }

    // prologue: W(0); act(0) -> A; act(1) -> B
    LOADW(Wa, 0);
    LOADA(xA, pA, 0);
    LOADA(xB, pB, 1);

    // s=0
    LOADW(Wz, 1); WRITEA(xA, pA, 0); LOADA(xA, pA, 2);
    lgkm0_barrier(); COMPUTE(Wa, 0); __builtin_amdgcn_sched_barrier(0);
    // s=1
    LOADW(Wa, 2); WRITEA(xB, pB, 1); LOADA(xB, pB, 3);
    lgkm0_barrier(); COMPUTE(Wz, 1); __builtin_amdgcn_sched_barrier(0);
    // s=2
    LOADW(Wz, 3); WRITEA(xA, pA, 0); LOADA(xA, pA, 4);
    lgkm0_barrier(); COMPUTE(Wa, 0); __builtin_amdgcn_sched_barrier(0);
    // s=3
    LOADW(Wa, 4); WRITEA(xB, pB, 1); LOADA(xB, pB, 5);
    lgkm0_barrier(); COMPUTE(Wz, 1); __builtin_amdgcn_sched_barrier(0);
    // s=4
    LOADW(Wz, 5); WRITEA(xA, pA, 0); LOADA(xA, pA, 6);
    lgkm0_barrier(); COMPUTE(Wa, 0); __builtin_amdgcn_sched_barrier(0);
    // s=5
    LOADW(Wa, 6); WRITEA(xB, pB, 1); LOADA(xB, pB, 7);
    lgkm0_barrier(); COMPUTE(Wz, 1); __builtin_amdgcn_sched_barrier(0);
    // s=6
    LOADW(Wz, 7); WRITEA(xA, pA, 0);
    lgkm0_barrier(); COMPUTE(Wa, 0); __builtin_amdgcn_sched_barrier(0);
    // s=7
    WRITEA(xB, pB, 1);
    lgkm0_barrier(); COMPUTE(Wz, 1); __builtin_amdgcn_sched_barrier(0);

#undef LOADW
#undef LOADA
#undef WRITEA
#undef COMPUTE

    if (isK) {
      uint16_t* Kp = Kb + (size_t)b * N_ * C_;
#pragma unroll
      for (int cf = 0; cf < 4; ++cf)
#pragma unroll
        for (int nf = 0; nf < 8; ++nf) {
          const f32x4 a = acc[cf * 8 + nf];
          uint2 pkv;
          pkv.x = pk2(a[0], a[1]);
          pkv.y = pk2(a[2], a[3]);
          *(uint2*)&Kp[(size_t)(n0 + nf * 16 + c15) * C_ + wc * 64 + cf * 16 + 4 * g] = pkv;
        }
    } else {
      uint16_t* Vp = Vb + (size_t)b * C_ * N_;
#pragma unroll
      for (int nf = 0; nf < 8; ++nf)
#pragma unroll
        for (int cf = 0; cf < 4; ++cf) {
          const f32x4 a = acc[nf * 4 + cf];
          uint2 pkv;
          pkv.x = pk2(a[0], a[1]);
          pkv.y = pk2(a[2], a[3]);
          *(uint2*)&Vp[(size_t)(wc * 64 + cf * 16 + c15) * N_ + n0 + nf * 16 + 4 * g] = pkv;
        }
    }
  } else {
    // ---- Q projection: 8 blocks x 64 q-rows ----
    __shared__ __align__(16) uint16_t qlds[8][64][40];
    const int qb = bid - 256;
    const int q0g = qb * 64;
    const int b = q0g >> 8, q0 = q0g & 255;
    const int r = t >> 3, c0 = (t & 7) * 32, s = t & 7;
    const float* Qrow = queries + (size_t)(q0g + r) * C_ + c0;
    const float* Erow = qembed + (size_t)(q0g + r) * C_ + c0;
#pragma unroll
    for (int ph = 0; ph < 2; ++ph) {
      float4 a4[4], e4[4];
#pragma unroll
      for (int k = 0; k < 4; ++k) a4[k] = reinterpret_cast<const float4*>(Qrow + ph * 16)[k];
#pragma unroll
      for (int k = 0; k < 4; ++k) e4[k] = reinterpret_cast<const float4*>(Erow + ph * 16)[k];
      const float* af = reinterpret_cast<const float*>(a4);
      const float* ef = reinterpret_cast<const float*>(e4);
#pragma unroll
      for (int i = 0; i < 16; ++i) {
        const int cl = ph * 16 + i;
        const int col = cl ^ (8 * ((r >> 3) & 3));
        qlds[s][r][col] = bfbits(af[i] + ef[i]);
      }
      __builtin_amdgcn_sched_barrier(0);
    }
    lgkm0_barrier();

    const int w = wid;  // head = w
    f32x4 acc[4][2];
#pragma unroll
    for (int nf = 0; nf < 2; ++nf) {
      const float bv = bias[w * 32 + nf * 16 + c15];
      const f32x4 iv = {bv, bv, bv, bv};
#pragma unroll
      for (int qf = 0; qf < 4; ++qf) acc[qf][nf] = iv;
    }
#pragma unroll
    for (int s8 = 0; s8 < 8; ++s8) {
      bf16x8 Bf[2];
#pragma unroll
      for (int nf = 0; nf < 2; ++nf)
        Bf[nf] = *reinterpret_cast<const bf16x8*>(
            wkv + (size_t)(w * 32 + nf * 16 + c15) * C_ + s8 * 32 + g * 8);
#pragma unroll
      for (int qf = 0; qf < 4; ++qf) {
        const int rr = qf * 16 + c15;
        const bf16x8 Af = *reinterpret_cast<const bf16x8*>(
            &qlds[s8][rr][8 * (g ^ ((rr >> 3) & 3))]);
#pragma unroll
        for (int nf = 0; nf < 2; ++nf)
          acc[qf][nf] = __builtin_amdgcn_mfma_f32_16x16x32_bf16(Af, Bf[nf], acc[qf][nf], 0, 0, 0);
      }
    }
#pragma unroll
    for (int qf = 0; qf < 4; ++qf)
#pragma unroll
      for (int nf = 0; nf < 2; ++nf)
#pragma unroll
        for (int j = 0; j < 4; ++j) {
          const int q = q0 + qf * 16 + 4 * g + j;
          const int dk = nf * 16 + c15;
          Qb[((size_t)(b * H_ + w) * Q_ + q) * D_ + dk] = f2bf(acc[qf][nf][j] * SCALE);
        }
  }
}

// ---------------------------------------------------------------------------
// Kernel 3: attention over an N-chunk of 512 keys, all 256 queries of one
// (b,h). Raw-barrier double-buffered K/V staging; mask words batched.
// ---------------------------------------------------------------------------
__global__ __launch_bounds__(512) void attn(const uint16_t* __restrict__ Qb,
                                            const uint16_t* __restrict__ Kb,
                                            const uint16_t* __restrict__ Vb,
                                            const uint32_t* __restrict__ mb,
                                            float* __restrict__ ctx_part,
                                            float* __restrict__ lsum_part) {
  const int bid = blockIdx.x;
  const int nc = bid & 31, h = (bid >> 5) & 7, b = bid >> 8;
  const int t = threadIdx.x, wid = t >> 6, lane = t & 63;
  const int g = lane >> 4, c15 = lane & 15;
  const int qw0 = wid * 32;
  const int nbase = nc * (N_ / NC_);
  constexpr int SS = (N_ / NC_) / 128;

  __shared__ __align__(16) uint16_t kst[2][128][40];
  __shared__ __align__(16) uint16_t vst[2][32][136];
  __shared__ __align__(16) uint16_t plds[8][32][40];

  const uint16_t* Qp = Qb + (size_t)(b * H_ + h) * Q_ * D_;
  bf16x8 qfr[2];
#pragma unroll
  for (int qf = 0; qf < 2; ++qf)
    qfr[qf] = *reinterpret_cast<const bf16x8*>(Qp + (size_t)(qw0 + qf * 16 + c15) * D_ + g * 8);

  f32x4 acc[2][2];
  const f32x4 zero4 = {0.f, 0.f, 0.f, 0.f};
#pragma unroll
  for (int qf = 0; qf < 2; ++qf)
#pragma unroll
    for (int dvf = 0; dvf < 2; ++dvf) acc[qf][dvf] = zero4;
  float lsum[2][4] = {};

  const uint32_t* mrow = mb + (size_t)b * Q_ * (N_ / 32);

  const int krow = t >> 2, kch = t & 3;
  const uint16_t* ksrc = Kb + ((size_t)(b * N_ + nbase + krow)) * C_ + h * D_ + kch * 8;
  const int vrow = t >> 4, vch = t & 15;
  const uint16_t* vsrc = Vb + ((size_t)(b * C_ + h * D_ + vrow)) * N_ + nbase + vch * 8;

  uint4 kreg = *(const uint4*)ksrc;
  uint4 vreg = *(const uint4*)vsrc;

  int cur = 0;
  for (int ss = 0; ss < SS; ++ss) {
    *(uint4*)&kst[cur][krow][kch * 8] = kreg;
    *(uint4*)&vst[cur][vrow][vch * 8] = vreg;
    if (ss < SS - 1) {
      kreg = *(const uint4*)(ksrc + (size_t)(ss + 1) * 128 * C_);
      vreg = *(const uint4*)(vsrc + (ss + 1) * 128);
    }
    lgkm0_barrier();

    const int nstart = nbase + ss * 128;
#pragma unroll
    for (int half = 0; half < 2; ++half) {
      uint32_t mw[2][4][2];
#pragma unroll
      for (int qf = 0; qf < 2; ++qf)
#pragma unroll
        for (int j = 0; j < 4; ++j) {
          const int q = qw0 + qf * 16 + 4 * g + j;
          const uint2 u = *reinterpret_cast<const uint2*>(
              &mrow[(size_t)q * (N_ / 32) + (nstart >> 5) + half * 2]);
          mw[qf][j][0] = u.x;
          mw[qf][j][1] = u.y;
        }
#pragma unroll
      for (int s2 = 0; s2 < 2; ++s2) {
        const int sub = half * 2 + s2;
        const int nl0 = sub * 32;
        bf16x8 kfr[2];
#pragma unroll
        for (int nf = 0; nf < 2; ++nf)
          kfr[nf] = *reinterpret_cast<const bf16x8*>(&kst[cur][nl0 + nf * 16 + c15][g * 8]);
        f32x4 s[2][2];
#pragma unroll
        for (int qf = 0; qf < 2; ++qf)
#pragma unroll
          for (int nf = 0; nf < 2; ++nf)
            s[qf][nf] = __builtin_amdgcn_mfma_f32_16x16x32_bf16(qfr[qf], kfr[nf], zero4, 0, 0, 0);

#pragma unroll
        for (int qf = 0; qf < 2; ++qf) {
#pragma unroll
          for (int j = 0; j < 4; ++j) {
            const uint32_t wmask = mw[qf][j][s2];
#pragma unroll
            for (int nf = 0; nf < 2; ++nf) {
              const int bit = nf * 16 + c15;
              const float p = ((wmask >> bit) & 1u) ? 0.0f : __expf(s[qf][nf][j]);
              lsum[qf][j] += p;
              plds[wid][qf * 16 + 4 * g + j][nf * 16 + c15] = f2bf(p);
            }
          }
        }
        __asm__ volatile("s_waitcnt lgkmcnt(0)" ::: "memory");
#pragma unroll
        for (int qf = 0; qf < 2; ++qf) {
          const bf16x8 pa = *reinterpret_cast<const bf16x8*>(&plds[wid][qf * 16 + c15][g * 8]);
#pragma unroll
          for (int dvf = 0; dvf < 2; ++dvf) {
            const bf16x8 vb =
                *reinterpret_cast<const bf16x8*>(&vst[cur][dvf * 16 + c15][nl0 + g * 8]);
            acc[qf][dvf] = __builtin_amdgcn_mfma_f32_16x16x32_bf16(pa, vb, acc[qf][dvf], 0, 0, 0);
          }
        }
      }
    }
    __builtin_amdgcn_sched_barrier(0);
    cur ^= 1;
  }

#pragma unroll
  for (int qf = 0; qf < 2; ++qf)
#pragma unroll
    for (int j = 0; j < 4; ++j) {
      float v = lsum[qf][j];
      v += __shfl_xor(v, 1, 64);
      v += __shfl_xor(v, 2, 64);
      v += __shfl_xor(v, 4, 64);
      v += __shfl_xor(v, 8, 64);
      lsum[qf][j] = v;
    }

  float* cp = ctx_part + ((size_t)(b * H_ + h) * NC_ + nc) * Q_ * D_;
#pragma unroll
  for (int qf = 0; qf < 2; ++qf)
#pragma unroll
    for (int dvf = 0; dvf < 2; ++dvf)
#pragma unroll
      for (int j = 0; j < 4; ++j) {
        const int q = qw0 + qf * 16 + 4 * g + j;
        cp[(size_t)q * D_ + dvf * 16 + c15] = acc[qf][dvf][j];
      }
  if (c15 == 0) {
    float* lp = lsum_part + ((size_t)(b * H_ + h) * NC_ + nc) * Q_;
#pragma unroll
    for (int qf = 0; qf < 2; ++qf)
#pragma unroll
      for (int j = 0; j < 4; ++j) lp[qw0 + qf * 16 + 4 * g + j] = lsum[qf][j];
  }
}

// ---------------------------------------------------------------------------
// Kernel 4: combine partials + out_proj (TRANSPOSED weights) + residual + LN.
// ---------------------------------------------------------------------------
__global__ __launch_bounds__(256) void epilogue(const float* __restrict__ ctx_part,
                                                const float* __restrict__ lsum_part,
                                                const float* __restrict__ queries,
                                                const float* __restrict__ woT,
                                                const float* __restrict__ bo,
                                                const float* __restrict__ gamma,
                                                const float* __restrict__ beta,
                                                float* __restrict__ out) {
  const int bq = blockIdx.x;
  const int b = bq >> 8, q = bq & 255;
  const int t = threadIdx.x;
  const int h = t >> 5, dv = t & 31;
  float cs = 0.f, ls = 0.f;
  for (int k = 0; k < NC_; ++k) {
    cs += ctx_part[(((size_t)(b * H_ + h) * NC_ + k) * Q_ + q) * D_ + dv];
    ls += lsum_part[((size_t)(b * H_ + h) * NC_ + k) * Q_ + q];
  }
  __shared__ float ctxrow[C_];
  ctxrow[t] = cs / ls;
  __syncthreads();
  float acc = bo[t];
#pragma unroll 8
  for (int j = 0; j < C_; ++j) acc = fmaf(ctxrow[j], woT[(size_t)j * C_ + t], acc);
  const float x = queries[(size_t)bq * C_ + t] + acc;
  float s1 = x, s2 = x * x;
  for (int o = 32; o > 0; o >>= 1) {
    s1 += __shfl_down(s1, o, 64);
    s2 += __shfl_down(s2, o, 64);
  }
  __shared__ float r1[4], r2[4];
  if ((t & 63) == 0) { r1[t >> 6] = s1; r2[t >> 6] = s2; }
  __syncthreads();
  const float mu = (r1[0] + r1[1] + r1[2] + r1[3]) * (1.0f / C_);
  const float e2 = (r2[0] + r2[1] + r2[2] + r2[3]) * (1.0f / C_);
  const float var = e2 - mu * mu;
  out[(size_t)bq * C_ + t] = (x - mu) * rsqrtf(var + 1e-5f) * gamma[t] + beta[t];
}

extern "C" void kernel_launch(void* const* d_in, const int* in_sizes, int n_in,
                              void* d_out, int out_size, void* d_ws, size_t ws_size,
                              hipStream_t stream) {
  const float* queries    = (const float*)d_in[0];
  const float* vidfeat    = (const float*)d_in[1];
  const float* vidmask    = (const float*)d_in[2];
  const float* posembed   = (const float*)d_in[3];
  const float* queryembed = (const float*)d_in[4];
  const float* inw        = (const float*)d_in[5];
  const float* inb        = (const float*)d_in[6];
  const float* outw       = (const float*)d_in[7];
  const float* outb       = (const float*)d_in[8];
  const float* gamma      = (const float*)d_in[9];
  const float* beta       = (const float*)d_in[10];
  float* out = (float*)d_out;

  char* ws = (char*)d_ws;
  size_t off = 0;
  uint16_t* Qb = (uint16_t*)(ws + off); off += (size_t)B_ * H_ * Q_ * D_ * 2;
  uint16_t* Kb = (uint16_t*)(ws + off); off += (size_t)B_ * N_ * C_ * 2;
  uint16_t* Vb = (uint16_t*)(ws + off); off += (size_t)B_ * C_ * N_ * 2;
  uint32_t* mb = (uint32_t*)(ws + off); off += (size_t)B_ * Q_ * (N_ / 32) * 4;
  float* ctxp  = (float*)(ws + off);    off += (size_t)B_ * H_ * NC_ * Q_ * D_ * 4;
  float* lsump = (float*)(ws + off);    off += (size_t)B_ * H_ * NC_ * Q_ * 4;
  uint16_t* wkv = (uint16_t*)(ws + off); off += (size_t)768 * C_ * 2;
  float* woT   = (float*)(ws + off);    off += (size_t)C_ * C_ * 4;

  prep<<<dim3(672), dim3(256), 0, stream>>>(inw, outw, vidmask, wkv, woT, mb);
  kvqproj<<<dim3(264), dim3(512), 0, stream>>>(vidfeat, posembed, queries, queryembed,
                                               wkv, inb, Kb, Vb, Qb);
  attn<<<dim3(B_ * H_ * NC_), dim3(512), 0, stream>>>(Qb, Kb, Vb, mb, ctxp, lsump);
  epilogue<<<dim3(B_ * Q_), dim3(256), 0, stream>>>(ctxp, lsump, queries, woT, outb, gamma, beta, out);
}

// Round 9
// 133.089 us; speedup vs baseline: 1.1429x; 1.1429x over previous
//
#include <hip/hip_runtime.h>
#include <stdint.h>

// CrossAttentionLayer: B=2, Q=256, N=16384, C=256, H=8, d=32
#define B_ 2
#define Q_ 256
#define N_ 16384
#define C_ 256
#define H_ 8
#define D_ 32
#define NC_ 32                      // attention split-N chunks (N/NC = 512 per block)
#define SCALE 0.17677669529663687f  // 1/sqrt(32)

typedef __bf16 bf16x8 __attribute__((ext_vector_type(8)));
typedef float f32x4 __attribute__((ext_vector_type(4)));

__device__ __forceinline__ uint16_t bfbits(float f) {
  union { __bf16 h; uint16_t u; } c;
  c.h = (__bf16)f;
  return c.u;
}
__device__ __forceinline__ uint16_t f2bf(float f) {
  union { float f; uint32_t u; } c; c.f = f;
  uint32_t r = c.u + 0x7FFFu + ((c.u >> 16) & 1u);  // RNE
  return (uint16_t)(r >> 16);
}
__device__ __forceinline__ uint32_t pk2(float a, float b) {
  return (uint32_t)f2bf(a) | ((uint32_t)f2bf(b) << 16);
}
__device__ __forceinline__ void lgkm0_barrier() {
  __builtin_amdgcn_sched_barrier(0);
  asm volatile("s_waitcnt lgkmcnt(0)" ::: "memory");
  __builtin_amdgcn_sched_barrier(0);
  __builtin_amdgcn_s_barrier();
  __builtin_amdgcn_sched_barrier(0);
}

// ---------------------------------------------------------------------------
// Kernel 1 "prep": blocks 0..95: in_proj_w (768x256) -> bf16; 96..159:
// woT = out_proj_w^T; 160..223: wqT = wq^T; 224..735: pack vid_mask ->
// bitmask (bit=1 => blocked) with all-blocked fallback.
// ---------------------------------------------------------------------------
__global__ __launch_bounds__(256) void prep(const float* __restrict__ inw,
                                            const float* __restrict__ outw,
                                            const float* __restrict__ vm,
                                            uint16_t* __restrict__ wb,
                                            float* __restrict__ woT,
                                            float* __restrict__ wqT,
                                            uint32_t* __restrict__ mb) {
  __shared__ __align__(16) char sh[4352];
  const int bid = blockIdx.x;
  const int t = threadIdx.x;
  if (bid < 96) {
    const int i = (bid * 256 + t) * 8;
    const float4 a = *reinterpret_cast<const float4*>(inw + i);
    const float4 b = *reinterpret_cast<const float4*>(inw + i + 4);
    ushort4 lo = {f2bf(a.x), f2bf(a.y), f2bf(a.z), f2bf(a.w)};
    ushort4 hi = {f2bf(b.x), f2bf(b.y), f2bf(b.z), f2bf(b.w)};
    *reinterpret_cast<ushort4*>(wb + i) = lo;
    *reinterpret_cast<ushort4*>(wb + i + 4) = hi;
  } else if (bid < 224) {
    float(*s)[33] = reinterpret_cast<float(*)[33]>(sh);
    const bool isWo = bid < 160;
    const int bb = bid - (isWo ? 96 : 160);
    const float* src = isWo ? outw : inw;   // wq = inw rows 0..255
    float* dst = isWo ? woT : wqT;
    const int bx = bb & 7, by = bb >> 3;
    const int r0 = by * 32, c0 = bx * 32;
    const int tr = t >> 5, tc = t & 31;
#pragma unroll
    for (int k = 0; k < 4; ++k)
      s[tr + 8 * k][tc] = src[(size_t)(r0 + tr + 8 * k) * 256 + c0 + tc];
    __syncthreads();
#pragma unroll
    for (int k = 0; k < 4; ++k)
      dst[(size_t)(c0 + tr + 8 * k) * 256 + r0 + tc] = s[tc][tr + 8 * k];
  } else {
    uint8_t(*nib)[256] = reinterpret_cast<uint8_t(*)[256]>(sh);
    __shared__ int wcnt[4];
    __shared__ int tot;
    const int bq = bid - 224;
    const float* row = vm + (size_t)bq * N_;
    const int lane = t & 63;
    int cnt = 0;
#pragma unroll
    for (int i = 0; i < 16; ++i) {
      const float4 v = *reinterpret_cast<const float4*>(&row[i * 1024 + 4 * t]);
      const uint32_t nb = (v.x < 0.5f ? 1u : 0u) | (v.y < 0.5f ? 2u : 0u) |
                          (v.z < 0.5f ? 4u : 0u) | (v.w < 0.5f ? 8u : 0u);
      nib[i][t] = (uint8_t)nb;
      cnt += __popc(nb);
    }
    for (int o = 32; o > 0; o >>= 1) cnt += __shfl_down(cnt, o, 64);
    if (lane == 0) wcnt[t >> 6] = cnt;
    __syncthreads();
    if (t == 0) tot = wcnt[0] + wcnt[1] + wcnt[2] + wcnt[3];
    __syncthreads();
    const bool allb = (tot == N_);
    uint32_t* dst = mb + (size_t)bq * 512;
#pragma unroll
    for (int k = 0; k < 2; ++k) {
      const int w = k * 256 + t;
      const int i = w >> 5, tw = w & 31;
      const uint2 u = *reinterpret_cast<const uint2*>(&nib[i][8 * tw]);
      uint32_t y0 = u.x & 0x0F0F0F0Fu; y0 = y0 | (y0 >> 4);
      uint32_t y1 = u.y & 0x0F0F0F0Fu; y1 = y1 | (y1 >> 4);
      const uint32_t word = (y0 & 0xFFu) | (((y0 >> 16) & 0xFFu) << 8) |
                            ((y1 & 0xFFu) << 16) | (((y1 >> 16) & 0xFFu) << 24);
      dst[w] = allb ? 0u : word;
    }
  }
}

// ---------------------------------------------------------------------------
// Kernel 2 "fuse": pure streaming, no LDS, no barriers (blocks 0..1023).
// Register 8x4 transpose: thread reads rows cg*8..cg*8+7 x float4 (wave reads
// 1 KB contiguous per row-instr), writes XP = bf16(vf+pe) and XV = bf16(vf)
// in frag8 layout [b][cg][n][8] (16B per (cg,n) = one MFMA k-octet).
// Blocks 1024..1151: scalar Q projection (wqT coalesced), 4 rows/block.
// ---------------------------------------------------------------------------
__global__ __launch_bounds__(256) void fuse(const float* __restrict__ vf,
                                            const float* __restrict__ pe,
                                            const float* __restrict__ queries,
                                            const float* __restrict__ qembed,
                                            const float* __restrict__ wqT,
                                            const float* __restrict__ bias,
                                            uint16_t* __restrict__ XP,
                                            uint16_t* __restrict__ XV,
                                            uint16_t* __restrict__ Qb) {
  const int bid = blockIdx.x;
  const int t = threadIdx.x;
  if (bid < 1024) {
    const int b = bid >> 9, cg = (bid >> 4) & 31, ch = bid & 15;
    const int nq = ch * 1024 + t * 4;
    const float* vb = vf + ((size_t)(b * 32 + cg) * 8) * N_ + nq;
    const float* pb = pe + ((size_t)(b * 32 + cg) * 8) * N_ + nq;
    float4 x[8], p[8];
#pragma unroll
    for (int r = 0; r < 8; ++r) x[r] = *reinterpret_cast<const float4*>(vb + (size_t)r * N_);
#pragma unroll
    for (int r = 0; r < 8; ++r) p[r] = *reinterpret_cast<const float4*>(pb + (size_t)r * N_);
    uint16_t* xpo = XP + ((size_t)(b * 32 + cg) * N_ + nq) * 8;
    uint16_t* xvo = XV + ((size_t)(b * 32 + cg) * N_ + nq) * 8;
#pragma unroll
    for (int i = 0; i < 4; ++i) {
      const float* fx[8];
      uint4 up, uv;
      const float x0 = ((const float*)&x[0])[i], x1 = ((const float*)&x[1])[i];
      const float x2 = ((const float*)&x[2])[i], x3 = ((const float*)&x[3])[i];
      const float x4 = ((const float*)&x[4])[i], x5 = ((const float*)&x[5])[i];
      const float x6 = ((const float*)&x[6])[i], x7 = ((const float*)&x[7])[i];
      const float p0 = ((const float*)&p[0])[i], p1 = ((const float*)&p[1])[i];
      const float p2 = ((const float*)&p[2])[i], p3 = ((const float*)&p[3])[i];
      const float p4 = ((const float*)&p[4])[i], p5 = ((const float*)&p[5])[i];
      const float p6 = ((const float*)&p[6])[i], p7 = ((const float*)&p[7])[i];
      up.x = pk2(x0 + p0, x1 + p1); up.y = pk2(x2 + p2, x3 + p3);
      up.z = pk2(x4 + p4, x5 + p5); up.w = pk2(x6 + p6, x7 + p7);
      uv.x = pk2(x0, x1); uv.y = pk2(x2, x3);
      uv.z = pk2(x4, x5); uv.w = pk2(x6, x7);
      *reinterpret_cast<uint4*>(xpo + (size_t)i * 8) = up;
      *reinterpret_cast<uint4*>(xvo + (size_t)i * 8) = uv;
      (void)fx;
    }
  } else {
    // scalar Q projection, 4 rows per block
    const int r0 = (bid - 1024) * 4;
    __shared__ float xq[4][C_];
#pragma unroll
    for (int r = 0; r < 4; ++r)
      xq[r][t] = queries[(size_t)(r0 + r) * C_ + t] + qembed[(size_t)(r0 + r) * C_ + t];
    __syncthreads();
    float a0 = bias[t], a1 = a0, a2 = a0, a3 = a0;
#pragma unroll 4
    for (int j = 0; j < C_; ++j) {
      const float wv = wqT[(size_t)j * C_ + t];
      a0 = fmaf(xq[0][j], wv, a0);
      a1 = fmaf(xq[1][j], wv, a1);
      a2 = fmaf(xq[2][j], wv, a2);
      a3 = fmaf(xq[3][j], wv, a3);
    }
    const int h = t >> 5, dk = t & 31;
    const float r4[4] = {a0, a1, a2, a3};
#pragma unroll
    for (int r = 0; r < 4; ++r) {
      const int bq = r0 + r;
      const int b = bq >> 8, q = bq & 255;
      Qb[((size_t)(b * H_ + h) * Q_ + q) * D_ + dk] = f2bf(r4[r] * SCALE);
    }
  }
}

// ---------------------------------------------------------------------------
// Kernel 3 "kvgemm<ISK>": no LDS, NO BARRIERS — waves fully independent.
// Per block (512 thr): 256 cout x 64 n; wave = (wc cout-64) x (wn n-32).
// B/A fragments read 256B-contiguous from frag8 XP/XV (L3-hot), weights from
// L2 (wkv bf16), 4-deep fragment prefetch ring, ~90 VGPR.
// ISK=1: K = wk@XP + bk -> Kh [b][h][n][32].
// ISK=0: V = wv@XV + bv -> Vh [b][h][32][n].
// ---------------------------------------------------------------------------
template <int ISK>
__global__ __launch_bounds__(512, 4) void kvgemm(const uint16_t* __restrict__ Xf,
                                                 const uint16_t* __restrict__ wkv,
                                                 const float* __restrict__ bias,
                                                 uint16_t* __restrict__ outp) {
  const int bid = blockIdx.x;
  const int b = bid >> 8, nt = bid & 255;
  const int t = threadIdx.x, wid = t >> 6, lane = t & 63;
  const int g = lane >> 4, c15 = lane & 15;
  const int wc = wid & 3;
  const int n0w = nt * 64 + (wid >> 2) * 32;

  const uint16_t* Wsec = wkv + (ISK ? 256 : 512) * C_ + (size_t)(wc * 64 + c15) * C_;
  const uint16_t* Xbase = Xf + ((size_t)(b * 32 + g) * N_ + n0w) * 8;

  f32x4 acc[8];
  if (ISK) {
#pragma unroll
    for (int cf = 0; cf < 4; ++cf) {
      f32x4 iv;
#pragma unroll
      for (int j = 0; j < 4; ++j) iv[j] = bias[256 + wc * 64 + cf * 16 + 4 * g + j];
      acc[cf * 2 + 0] = iv;
      acc[cf * 2 + 1] = iv;
    }
  } else {
#pragma unroll
    for (int cf = 0; cf < 4; ++cf) {
      const float bv = bias[512 + wc * 64 + cf * 16 + c15];
      const f32x4 iv = {bv, bv, bv, bv};
      acc[0 * 4 + cf] = iv;
      acc[1 * 4 + cf] = iv;
    }
  }

  bf16x8 Bf[4][2], Wfa[4], Wfb[4];

#define LOADB(s)                                                              \
  {                                                                           \
    _Pragma("unroll") for (int nf = 0; nf < 2; ++nf)                          \
        Bf[(s) & 3][nf] = *reinterpret_cast<const bf16x8*>(                   \
            Xbase + ((size_t)(s) * 4 * N_ + nf * 16 + c15) * 8);              \
  }
#define LOADW(W, s)                                                           \
  {                                                                           \
    _Pragma("unroll") for (int cf = 0; cf < 4; ++cf)                          \
        W[cf] = *reinterpret_cast<const bf16x8*>(                             \
            Wsec + (size_t)cf * 16 * C_ + (s) * 32 + g * 8);                  \
  }
#define COMPUTE(W, s)                                                         \
  {                                                                           \
    _Pragma("unroll") for (int nf = 0; nf < 2; ++nf) {                        \
      if (ISK) {                                                              \
        _Pragma("unroll") for (int cf = 0; cf < 4; ++cf)                      \
            acc[cf * 2 + nf] = __builtin_amdgcn_mfma_f32_16x16x32_bf16(       \
                W[cf], Bf[(s) & 3][nf], acc[cf * 2 + nf], 0, 0, 0);           \
      } else {                                                                \
        _Pragma("unroll") for (int cf = 0; cf < 4; ++cf)                      \
            acc[nf * 4 + cf] = __builtin_amdgcn_mfma_f32_16x16x32_bf16(       \
                Bf[(s) & 3][nf], W[cf], acc[nf * 4 + cf], 0, 0, 0);           \
      }                                                                       \
    }                                                                         \
  }

  // 4-deep activation prefetch; weights one step ahead, issued AFTER the
  // corresponding deeper act loads (in-order vmcnt => act stream never stalls
  // on a weight wait it didn't already need).
  LOADB(0); LOADB(1); LOADB(2); LOADB(3);
  LOADW(Wfa, 0);
  // s=0
  LOADB(4); LOADW(Wfb, 1); COMPUTE(Wfa, 0);
  // s=1
  LOADB(5); LOADW(Wfa, 2); COMPUTE(Wfb, 1);
  // s=2
  LOADB(6); LOADW(Wfb, 3); COMPUTE(Wfa, 2);
  // s=3
  LOADB(7); LOADW(Wfa, 4); COMPUTE(Wfb, 3);
  // s=4
  LOADW(Wfb, 5); COMPUTE(Wfa, 4);
  // s=5
  LOADW(Wfa, 6); COMPUTE(Wfb, 5);
  // s=6
  LOADW(Wfb, 7); COMPUTE(Wfa, 6);
  // s=7
  COMPUTE(Wfb, 7);

#undef LOADB
#undef LOADW
#undef COMPUTE

  if (ISK) {
    // Kh[b][h][n][32], lane holds 4 consecutive dk at fixed n
#pragma unroll
    for (int cf = 0; cf < 4; ++cf) {
      const int h = wc * 2 + (cf >> 1);
      const int dkb = (cf & 1) * 16 + 4 * g;
#pragma unroll
      for (int nf = 0; nf < 2; ++nf) {
        const f32x4 a = acc[cf * 2 + nf];
        uint2 pkv;
        pkv.x = pk2(a[0], a[1]);
        pkv.y = pk2(a[2], a[3]);
        const int n = n0w + nf * 16 + c15;
        *reinterpret_cast<uint2*>(
            &outp[((size_t)(b * H_ + h) * N_ + n) * 32 + dkb]) = pkv;
      }
    }
  } else {
    // Vh[b][h][32][n], lane holds 4 consecutive n at fixed dv
#pragma unroll
    for (int cf = 0; cf < 4; ++cf) {
      const int cout = wc * 64 + cf * 16 + c15;
      const int h = cout >> 5, dv = cout & 31;
#pragma unroll
      for (int nf = 0; nf < 2; ++nf) {
        const f32x4 a = acc[nf * 4 + cf];
        uint2 pkv;
        pkv.x = pk2(a[0], a[1]);
        pkv.y = pk2(a[2], a[3]);
        *reinterpret_cast<uint2*>(
            &outp[((size_t)(b * H_ + h) * 32 + dv) * N_ + n0w + nf * 16 + 4 * g]) = pkv;
      }
    }
  }
}

// ---------------------------------------------------------------------------
// Kernel 4: attention over an N-chunk of 512 keys, all 256 queries of one
// (b,h). K-stage is now an 8KB CONTIGUOUS copy (Kh layout); V rows 256B.
// ---------------------------------------------------------------------------
__global__ __launch_bounds__(512) void attn(const uint16_t* __restrict__ Qb,
                                            const uint16_t* __restrict__ Kh,
                                            const uint16_t* __restrict__ Vh,
                                            const uint32_t* __restrict__ mb,
                                            float* __restrict__ ctx_part,
                                            float* __restrict__ lsum_part) {
  const int bid = blockIdx.x;
  const int nc = bid & 31, h = (bid >> 5) & 7, b = bid >> 8;
  const int t = threadIdx.x, wid = t >> 6, lane = t & 63;
  const int g = lane >> 4, c15 = lane & 15;
  const int qw0 = wid * 32;
  const int nbase = nc * (N_ / NC_);
  constexpr int SS = (N_ / NC_) / 128;

  __shared__ __align__(16) uint16_t kst[2][128][40];
  __shared__ __align__(16) uint16_t vst[2][32][136];
  __shared__ __align__(16) uint16_t plds[8][32][40];

  const uint16_t* Qp = Qb + (size_t)(b * H_ + h) * Q_ * D_;
  bf16x8 qfr[2];
#pragma unroll
  for (int qf = 0; qf < 2; ++qf)
    qfr[qf] = *reinterpret_cast<const bf16x8*>(Qp + (size_t)(qw0 + qf * 16 + c15) * D_ + g * 8);

  f32x4 acc[2][2];
  const f32x4 zero4 = {0.f, 0.f, 0.f, 0.f};
#pragma unroll
  for (int qf = 0; qf < 2; ++qf)
#pragma unroll
    for (int dvf = 0; dvf < 2; ++dvf) acc[qf][dvf] = zero4;
  float lsum[2][4] = {};

  const uint32_t* mrow = mb + (size_t)b * Q_ * (N_ / 32);

  const int krow = t >> 2, kch = t & 3;
  const uint16_t* ksrc = Kh + ((size_t)(b * H_ + h) * N_ + nbase + krow) * 32 + kch * 8;
  const int vrow = t >> 4, vch = t & 15;
  const uint16_t* vsrc = Vh + ((size_t)(b * H_ + h) * 32 + vrow) * N_ + nbase + vch * 8;

  uint4 kreg = *(const uint4*)ksrc;
  uint4 vreg = *(const uint4*)vsrc;

  int cur = 0;
  for (int ss = 0; ss < SS; ++ss) {
    *(uint4*)&kst[cur][krow][kch * 8] = kreg;
    *(uint4*)&vst[cur][vrow][vch * 8] = vreg;
    if (ss < SS - 1) {
      kreg = *(const uint4*)(ksrc + (size_t)(ss + 1) * 128 * 32);
      vreg = *(const uint4*)(vsrc + (ss + 1) * 128);
    }
    lgkm0_barrier();

    const int nstart = nbase + ss * 128;
#pragma unroll
    for (int half = 0; half < 2; ++half) {
      uint32_t mw[2][4][2];
#pragma unroll
      for (int qf = 0; qf < 2; ++qf)
#pragma unroll
        for (int j = 0; j < 4; ++j) {
          const int q = qw0 + qf * 16 + 4 * g + j;
          const uint2 u = *reinterpret_cast<const uint2*>(
              &mrow[(size_t)q * (N_ / 32) + (nstart >> 5) + half * 2]);
          mw[qf][j][0] = u.x;
          mw[qf][j][1] = u.y;
        }
#pragma unroll
      for (int s2 = 0; s2 < 2; ++s2) {
        const int sub = half * 2 + s2;
        const int nl0 = sub * 32;
        bf16x8 kfr[2];
#pragma unroll
        for (int nf = 0; nf < 2; ++nf)
          kfr[nf] = *reinterpret_cast<const bf16x8*>(&kst[cur][nl0 + nf * 16 + c15][g * 8]);
        f32x4 s[2][2];
#pragma unroll
        for (int qf = 0; qf < 2; ++qf)
#pragma unroll
          for (int nf = 0; nf < 2; ++nf)
            s[qf][nf] = __builtin_amdgcn_mfma_f32_16x16x32_bf16(qfr[qf], kfr[nf], zero4, 0, 0, 0);

#pragma unroll
        for (int qf = 0; qf < 2; ++qf) {
#pragma unroll
          for (int j = 0; j < 4; ++j) {
            const uint32_t wmask = mw[qf][j][s2];
#pragma unroll
            for (int nf = 0; nf < 2; ++nf) {
              const int bit = nf * 16 + c15;
              const float p = ((wmask >> bit) & 1u) ? 0.0f : __expf(s[qf][nf][j]);
              lsum[qf][j] += p;
              plds[wid][qf * 16 + 4 * g + j][nf * 16 + c15] = f2bf(p);
            }
          }
        }
        __asm__ volatile("s_waitcnt lgkmcnt(0)" ::: "memory");
#pragma unroll
        for (int qf = 0; qf < 2; ++qf) {
          const bf16x8 pa = *reinterpret_cast<const bf16x8*>(&plds[wid][qf * 16 + c15][g * 8]);
#pragma unroll
          for (int dvf = 0; dvf < 2; ++dvf) {
            const bf16x8 vb =
                *reinterpret_cast<const bf16x8*>(&vst[cur][dvf * 16 + c15][nl0 + g * 8]);
            acc[qf][dvf] = __builtin_amdgcn_mfma_f32_16x16x32_bf16(pa, vb, acc[qf][dvf], 0, 0, 0);
          }
        }
      }
    }
    __builtin_amdgcn_sched_barrier(0);
    cur ^= 1;
  }

#pragma unroll
  for (int qf = 0; qf < 2; ++qf)
#pragma unroll
    for (int j = 0; j < 4; ++j) {
      float v = lsum[qf][j];
      v += __shfl_xor(v, 1, 64);
      v += __shfl_xor(v, 2, 64);
      v += __shfl_xor(v, 4, 64);
      v += __shfl_xor(v, 8, 64);
      lsum[qf][j] = v;
    }

  float* cp = ctx_part + ((size_t)(b * H_ + h) * NC_ + nc) * Q_ * D_;
#pragma unroll
  for (int qf = 0; qf < 2; ++qf)
#pragma unroll
    for (int dvf = 0; dvf < 2; ++dvf)
#pragma unroll
      for (int j = 0; j < 4; ++j) {
        const int q = qw0 + qf * 16 + 4 * g + j;
        cp[(size_t)q * D_ + dvf * 16 + c15] = acc[qf][dvf][j];
      }
  if (c15 == 0) {
    float* lp = lsum_part + ((size_t)(b * H_ + h) * NC_ + nc) * Q_;
#pragma unroll
    for (int qf = 0; qf < 2; ++qf)
#pragma unroll
      for (int j = 0; j < 4; ++j) lp[qw0 + qf * 16 + 4 * g + j] = lsum[qf][j];
  }
}

// ---------------------------------------------------------------------------
// Kernel 5: combine partials + out_proj (woT) + residual + LayerNorm.
// ---------------------------------------------------------------------------
__global__ __launch_bounds__(256) void epilogue(const float* __restrict__ ctx_part,
                                                const float* __restrict__ lsum_part,
                                                const float* __restrict__ queries,
                                                const float* __restrict__ woT,
                                                const float* __restrict__ bo,
                                                const float* __restrict__ gamma,
                                                const float* __restrict__ beta,
                                                float* __restrict__ out) {
  const int bq = blockIdx.x;
  const int b = bq >> 8, q = bq & 255;
  const int t = threadIdx.x;
  const int h = t >> 5, dv = t & 31;
  float cs = 0.f, ls = 0.f;
  for (int k = 0; k < NC_; ++k) {
    cs += ctx_part[(((size_t)(b * H_ + h) * NC_ + k) * Q_ + q) * D_ + dv];
    ls += lsum_part[((size_t)(b * H_ + h) * NC_ + k) * Q_ + q];
  }
  __shared__ float ctxrow[C_];
  ctxrow[t] = cs / ls;
  __syncthreads();
  float acc = bo[t];
#pragma unroll 8
  for (int j = 0; j < C_; ++j) acc = fmaf(ctxrow[j], woT[(size_t)j * C_ + t], acc);
  const float x = queries[(size_t)bq * C_ + t] + acc;
  float s1 = x, s2 = x * x;
  for (int o = 32; o > 0; o >>= 1) {
    s1 += __shfl_down(s1, o, 64);
    s2 += __shfl_down(s2, o, 64);
  }
  __shared__ float r1[4], r2[4];
  if ((t & 63) == 0) { r1[t >> 6] = s1; r2[t >> 6] = s2; }
  __syncthreads();
  const float mu = (r1[0] + r1[1] + r1[2] + r1[3]) * (1.0f / C_);
  const float e2 = (r2[0] + r2[1] + r2[2] + r2[3]) * (1.0f / C_);
  const float var = e2 - mu * mu;
  out[(size_t)bq * C_ + t] = (x - mu) * rsqrtf(var + 1e-5f) * gamma[t] + beta[t];
}

extern "C" void kernel_launch(void* const* d_in, const int* in_sizes, int n_in,
                              void* d_out, int out_size, void* d_ws, size_t ws_size,
                              hipStream_t stream) {
  const float* queries    = (const float*)d_in[0];
  const float* vidfeat    = (const float*)d_in[1];
  const float* vidmask    = (const float*)d_in[2];
  const float* posembed   = (const float*)d_in[3];
  const float* queryembed = (const float*)d_in[4];
  const float* inw        = (const float*)d_in[5];
  const float* inb        = (const float*)d_in[6];
  const float* outw       = (const float*)d_in[7];
  const float* outb       = (const float*)d_in[8];
  const float* gamma      = (const float*)d_in[9];
  const float* beta       = (const float*)d_in[10];
  float* out = (float*)d_out;

  char* ws = (char*)d_ws;
  size_t off = 0;
  uint16_t* Qb  = (uint16_t*)(ws + off); off += (size_t)B_ * H_ * Q_ * D_ * 2;       // 256 KB
  uint16_t* Kh  = (uint16_t*)(ws + off); off += (size_t)B_ * H_ * N_ * D_ * 2;       // 16.78 MB
  uint16_t* Vh  = (uint16_t*)(ws + off); off += (size_t)B_ * H_ * D_ * N_ * 2;       // 16.78 MB
  uint32_t* mb  = (uint32_t*)(ws + off); off += (size_t)B_ * Q_ * (N_ / 32) * 4;     // 1 MB
  uint16_t* wkv = (uint16_t*)(ws + off); off += (size_t)768 * C_ * 2;                // 384 KB
  float* woT    = (float*)(ws + off);    off += (size_t)C_ * C_ * 4;                 // 256 KB
  float* wqT    = (float*)(ws + off);    off += (size_t)C_ * C_ * 4;                 // 256 KB
  uint16_t* XP  = (uint16_t*)(ws + off); off += (size_t)B_ * C_ * N_ * 2;            // 16.78 MB
  uint16_t* XV  = (uint16_t*)(ws + off); off += (size_t)B_ * C_ * N_ * 2;            // 16.78 MB
  // ctx/lsum partials alias XP/XV (dead by the time attn writes them)
  float* ctxp  = (float*)XP;   // 16.78 MB needed, fits in XP
  float* lsump = (float*)XV;   // 1 MB needed, fits in XV

  prep<<<dim3(736), dim3(256), 0, stream>>>(inw, outw, vidmask, wkv, woT, wqT, mb);
  fuse<<<dim3(1152), dim3(256), 0, stream>>>(vidfeat, posembed, queries, queryembed,
                                             wqT, inb, XP, XV, Qb);
  kvgemm<1><<<dim3(512), dim3(512), 0, stream>>>(XP, wkv, inb, Kh);
  kvgemm<0><<<dim3(512), dim3(512), 0, stream>>>(XV, wkv, inb, Vh);
  attn<<<dim3(B_ * H_ * NC_), dim3(512), 0, stream>>>(Qb, Kh, Vh, mb, ctxp, lsump);
  epilogue<<<dim3(B_ * Q_), dim3(256), 0, stream>>>(ctxp, lsump, queries, woT, outb,
                                                    gamma, beta, out);
}